// Round 2
// baseline (1019.615 us; speedup 1.0000x reference)
//
#include <hip/hip_runtime.h>

// R-GCN layer: out[v] = sum_{e: dst[e]=v} norm[e] * (h[src[e]] @ W[rel[e]])
//
// R2 strategy: bucket edges by (dst_block_of_64, rel) -> 782*32 = 25024 buckets.
// One GPU block per dst-block accumulates all messages into an LDS tile
// (64 rows x 65-float padded stride) via LDS atomics, iterating rel buckets
// with per-rel W fragments in registers and mfma_f32_16x16x32_bf16.
// Output written once, coalesced. No global atomics on out.

#define N_NODES 50000
#define N_EDGES 1600000
#define D 64
#define N_REL 32

#define NBLK 782                 // ceil(50000/64) dst blocks
#define NB (NBLK * N_REL)        // 25024 buckets
#define HIST_BLOCKS 782          // ceil(1.6M / 2048)
#define LDS_STRIDE 65

typedef __attribute__((ext_vector_type(8))) __bf16 bf16x8;
typedef __attribute__((ext_vector_type(4))) float f32x4;

// ws layout (bytes):
//   [0, NB*4)          g_count
//   [NB*4, 2*NB*4)     g_base
//   [2*NB*4, 3*NB*4)   g_cursor
//   [3*NB*4, ...)      bpack[N_EDGES] (src | dst_local<<16), bnorm[N_EDGES]

__global__ __launch_bounds__(256) void k_zero(int* __restrict__ g_count) {
    int i = blockIdx.x * blockDim.x + threadIdx.x;
    if (i < NB) g_count[i] = 0;
}

__global__ __launch_bounds__(256) void k_hist(const int* __restrict__ dst,
                                              const int* __restrict__ rel,
                                              int* __restrict__ g_count) {
    int e = blockIdx.x * 2048 + threadIdx.x;
    #pragma unroll
    for (int rnd = 0; rnd < 8; ++rnd, e += 256) {
        if (e < N_EDGES) {
            int key = (dst[e] >> 6) * N_REL + rel[e];
            atomicAdd(&g_count[key], 1);
        }
    }
}

__global__ __launch_bounds__(256) void k_scan(const int* __restrict__ g_count,
                                              int* __restrict__ g_base,
                                              int* __restrict__ g_cursor) {
    __shared__ int wt[4];
    __shared__ int wbase[4];
    const int t = threadIdx.x;
    const int lane = t & 63, wid = t >> 6;
    const int PER = (NB + 255) / 256;     // 98
    const int lo = t * PER;
    const int hi = min(lo + PER, NB);
    int s = 0;
    for (int i = lo; i < hi; ++i) s += g_count[i];
    int incl = s;
    #pragma unroll
    for (int d = 1; d < 64; d <<= 1) {
        int v = __shfl_up(incl, d, 64);
        if (lane >= d) incl += v;
    }
    if (lane == 63) wt[wid] = incl;
    __syncthreads();
    if (t == 0) {
        int a = 0;
        for (int i = 0; i < 4; ++i) { wbase[i] = a; a += wt[i]; }
    }
    __syncthreads();
    int excl = wbase[wid] + incl - s;
    for (int i = lo; i < hi; ++i) {
        g_base[i] = excl;
        g_cursor[i] = excl;
        excl += g_count[i];
    }
}

__global__ __launch_bounds__(256) void k_scatter(
        const int* __restrict__ src, const int* __restrict__ dst,
        const int* __restrict__ rel, const float* __restrict__ norm,
        int* __restrict__ g_cursor,
        int* __restrict__ bpack, float* __restrict__ bnorm) {
    int e = blockIdx.x * 2048 + threadIdx.x;
    #pragma unroll
    for (int rnd = 0; rnd < 8; ++rnd, e += 256) {
        if (e < N_EDGES) {
            int d = dst[e];
            int key = (d >> 6) * N_REL + rel[e];
            int pos = atomicAdd(&g_cursor[key], 1);
            bpack[pos] = src[e] | ((d & 63) << 16);
            bnorm[pos] = norm[e];
        }
    }
}

__global__ __launch_bounds__(256) void k_gemm(
        const float* __restrict__ h, const float* __restrict__ W,
        const int* __restrict__ g_base, const int* __restrict__ g_count,
        const int* __restrict__ bpack, const float* __restrict__ bnorm,
        float* __restrict__ out) {
    __shared__ float accs[64 * LDS_STRIDE];

    for (int i = threadIdx.x; i < 64 * LDS_STRIDE; i += 256) accs[i] = 0.f;
    __syncthreads();

    const int w = threadIdx.x >> 6;
    const int lane = threadIdx.x & 63;
    const int m = lane & 15;     // A row within 16-edge tile / C col
    const int q = lane >> 4;     // quad
    const f32x4 vzero = {0.f, 0.f, 0.f, 0.f};

    // wave w handles rels w, w+4, ..., w+28
    for (int j = 0; j < 8; ++j) {
        const int r = w + j * 4;
        const int b = blockIdx.x * N_REL + r;
        const int cnt = g_count[b];
        if (cnt == 0) continue;
        const int base = g_base[b];

        // B fragments for W[r]: lane holds (kt,nt) elem j at
        // k = kt*32 + q*8 + j, n = nt*16 + m
        const float* Wr = W + (size_t)r * D * D;
        bf16x8 Bfrag[2][4];
        #pragma unroll
        for (int kt = 0; kt < 2; ++kt) {
            #pragma unroll
            for (int nt = 0; nt < 4; ++nt) {
                bf16x8 bb;
                #pragma unroll
                for (int jj = 0; jj < 8; ++jj)
                    bb[jj] = (__bf16)Wr[(kt * 32 + q * 8 + jj) * D + nt * 16 + m];
                Bfrag[kt][nt] = bb;
            }
        }

        for (int e0 = 0; e0 < cnt; e0 += 16) {
            int er = min(e0 + m, cnt - 1);
            int s = bpack[base + er] & 0xFFFF;
            const float* hrow = h + (size_t)s * D;

            f32x4 acc[4];
            #pragma unroll
            for (int nt = 0; nt < 4; ++nt) acc[nt] = vzero;

            #pragma unroll
            for (int kt = 0; kt < 2; ++kt) {
                const float4* ap = (const float4*)(hrow + kt * 32 + q * 8);
                float4 a0 = ap[0];
                float4 a1 = ap[1];
                bf16x8 a;
                a[0] = (__bf16)a0.x; a[1] = (__bf16)a0.y; a[2] = (__bf16)a0.z; a[3] = (__bf16)a0.w;
                a[4] = (__bf16)a1.x; a[5] = (__bf16)a1.y; a[6] = (__bf16)a1.z; a[7] = (__bf16)a1.w;
                #pragma unroll
                for (int nt = 0; nt < 4; ++nt)
                    acc[nt] = __builtin_amdgcn_mfma_f32_16x16x32_bf16(a, Bfrag[kt][nt], acc[nt], 0, 0, 0);
            }

            // C row = q*4 + reg (edge within tile), col = nt*16 + m
            #pragma unroll
            for (int reg = 0; reg < 4; ++reg) {
                int erc = e0 + q * 4 + reg;
                if (erc < cnt) {
                    int pk = bpack[base + erc];
                    float nv = bnorm[base + erc];
                    int row = pk >> 16;
                    #pragma unroll
                    for (int nt = 0; nt < 4; ++nt)
                        atomicAdd(&accs[row * LDS_STRIDE + nt * 16 + m], acc[nt][reg] * nv);
                }
            }
        }
    }

    __syncthreads();

    // Write 64 output rows once, coalesced.
    const int node0 = blockIdx.x * 64;
    for (int i = threadIdx.x; i < 64 * 64; i += 256) {
        int row = i >> 6;
        int col = i & 63;
        int node = node0 + row;
        if (node < N_NODES) out[(size_t)node * D + col] = accs[row * LDS_STRIDE + col];
    }
}

extern "C" void kernel_launch(void* const* d_in, const int* in_sizes, int n_in,
                              void* d_out, int out_size, void* d_ws, size_t ws_size,
                              hipStream_t stream) {
    const float* h    = (const float*)d_in[0];
    const float* W    = (const float*)d_in[1];
    const int*   src  = (const int*)d_in[2];
    const int*   dst  = (const int*)d_in[3];
    const int*   rel  = (const int*)d_in[4];
    const float* norm = (const float*)d_in[5];
    float* out = (float*)d_out;

    char* ws = (char*)d_ws;
    int* g_count  = (int*)(ws);
    int* g_base   = (int*)(ws + (size_t)NB * 4);
    int* g_cursor = (int*)(ws + (size_t)NB * 8);
    int* bpack    = (int*)(ws + (size_t)NB * 12);
    float* bnorm  = (float*)(ws + (size_t)NB * 12 + (size_t)N_EDGES * 4);

    k_zero<<<(NB + 255) / 256, 256, 0, stream>>>(g_count);
    k_hist<<<HIST_BLOCKS, 256, 0, stream>>>(dst, rel, g_count);
    k_scan<<<1, 256, 0, stream>>>(g_count, g_base, g_cursor);
    k_scatter<<<HIST_BLOCKS, 256, 0, stream>>>(src, dst, rel, norm, g_cursor, bpack, bnorm);
    k_gemm<<<NBLK, 256, 0, stream>>>(h, W, g_base, g_count, bpack, bnorm, out);
}

// Round 3
// 992.089 us; speedup vs baseline: 1.0277x; 1.0277x over previous
//
#include <hip/hip_runtime.h>

// R-GCN layer: out[v] = sum_{e: dst[e]=v} norm[e] * (h[src[e]] @ W[rel[e]])
//
// R3: (dst_block_of_64, rel) bucketing as R2, with the latency killers fixed:
//  - W precomputed as bf16 fragment-ordered Wf (8 coalesced 16B loads per rel)
//  - h precomputed as bf16 (A-gather = two 16B loads/lane, L2/L3 resident)
//  - 512-thread blocks, 4 rels per wave -> ~24 waves/CU
//  - scatter writes one int2 per edge (src|row<<16, norm bits)

#define N_NODES 50000
#define N_EDGES 1600000
#define D 64
#define N_REL 32

#define NBLK 782                 // ceil(50000/64)
#define NB (NBLK * N_REL)        // 25024 buckets
#define HIST_BLOCKS 782          // ceil(1.6M/2048)
#define LDS_STRIDE 65

// k_prep grid split
#define PREP_H_BLOCKS 1563       // 3.2M bf16 / (256*8)
#define PREP_W_BLOCKS 64         // 16384 frag-lanes / 256
#define PREP_Z_BLOCKS 25         // 6256 int4 / 256
#define PREP_BLOCKS (PREP_H_BLOCKS + PREP_W_BLOCKS + PREP_Z_BLOCKS)

typedef __attribute__((ext_vector_type(8))) __bf16 bf16x8;
typedef __attribute__((ext_vector_type(4))) float f32x4;

// ws layout (bytes):
//   [0, NB*4)                       g_count
//   [NB*4, NB*8)                    g_base
//   [NB*8, NB*12)                   g_cursor
//   [300288, +12.8MB)               bpack[N_EDGES] int2
//   [13100288, +6.4MB)              h_bf16 (3.2M bf16)
//   [19500288, +256KB)              Wf (16384 bf16x8)
#define OFF_BPACK 300288
#define OFF_HB    13100288
#define OFF_WF    19500288

__global__ __launch_bounds__(256) void k_prep(const float* __restrict__ h,
                                              const float* __restrict__ W,
                                              int* __restrict__ g_count,
                                              bf16x8* __restrict__ hb8,
                                              bf16x8* __restrict__ wf8) {
    int b = blockIdx.x;
    if (b < PREP_H_BLOCKS) {
        int i = b * 256 + threadIdx.x;          // group of 8 floats
        if (i < 400000) {
            const float4* hp = (const float4*)h;
            float4 a0 = hp[i * 2];
            float4 a1 = hp[i * 2 + 1];
            bf16x8 v;
            v[0] = (__bf16)a0.x; v[1] = (__bf16)a0.y; v[2] = (__bf16)a0.z; v[3] = (__bf16)a0.w;
            v[4] = (__bf16)a1.x; v[5] = (__bf16)a1.y; v[6] = (__bf16)a1.z; v[7] = (__bf16)a1.w;
            hb8[i] = v;
        }
    } else if (b < PREP_H_BLOCKS + PREP_W_BLOCKS) {
        int i = (b - PREP_H_BLOCKS) * 256 + threadIdx.x;   // 0..16383 frag-lane
        int lane = i & 63;
        int frag = i >> 6;                  // (r*2 + kt)*4 + nt
        int nt = frag & 3;
        int kt = (frag >> 2) & 1;
        int r = frag >> 3;
        int m = lane & 15, q = lane >> 4;
        const float* Wr = W + (size_t)r * D * D;
        bf16x8 v;
        #pragma unroll
        for (int j = 0; j < 8; ++j)
            v[j] = (__bf16)Wr[(kt * 32 + q * 8 + j) * D + nt * 16 + m];
        wf8[i] = v;
    } else {
        int i = (b - PREP_H_BLOCKS - PREP_W_BLOCKS) * 256 + threadIdx.x;
        if (i < (NB + 3) / 4) ((int4*)g_count)[i] = make_int4(0, 0, 0, 0);
    }
}

__global__ __launch_bounds__(256) void k_hist(const int* __restrict__ dst,
                                              const int* __restrict__ rel,
                                              int* __restrict__ g_count) {
    int e = blockIdx.x * 2048 + threadIdx.x;
    #pragma unroll
    for (int rnd = 0; rnd < 8; ++rnd, e += 256) {
        if (e < N_EDGES) {
            int key = (dst[e] >> 6) * N_REL + rel[e];
            atomicAdd(&g_count[key], 1);
        }
    }
}

__global__ __launch_bounds__(256) void k_scan(const int* __restrict__ g_count,
                                              int* __restrict__ g_base,
                                              int* __restrict__ g_cursor) {
    __shared__ int wt[4];
    __shared__ int wbase[4];
    const int t = threadIdx.x;
    const int lane = t & 63, wid = t >> 6;
    const int PER = (NB + 255) / 256;
    const int lo = t * PER;
    const int hi = min(lo + PER, NB);
    int s = 0;
    for (int i = lo; i < hi; ++i) s += g_count[i];
    int incl = s;
    #pragma unroll
    for (int d = 1; d < 64; d <<= 1) {
        int v = __shfl_up(incl, d, 64);
        if (lane >= d) incl += v;
    }
    if (lane == 63) wt[wid] = incl;
    __syncthreads();
    if (t == 0) {
        int a = 0;
        for (int i = 0; i < 4; ++i) { wbase[i] = a; a += wt[i]; }
    }
    __syncthreads();
    int excl = wbase[wid] + incl - s;
    for (int i = lo; i < hi; ++i) {
        g_base[i] = excl;
        g_cursor[i] = excl;
        excl += g_count[i];
    }
}

__global__ __launch_bounds__(256) void k_scatter(
        const int* __restrict__ src, const int* __restrict__ dst,
        const int* __restrict__ rel, const float* __restrict__ norm,
        int* __restrict__ g_cursor, int2* __restrict__ bpack) {
    int e = blockIdx.x * 2048 + threadIdx.x;
    #pragma unroll
    for (int rnd = 0; rnd < 8; ++rnd, e += 256) {
        if (e < N_EDGES) {
            int d = dst[e];
            int key = (d >> 6) * N_REL + rel[e];
            int pos = atomicAdd(&g_cursor[key], 1);
            bpack[pos] = make_int2(src[e] | ((d & 63) << 16), __float_as_int(norm[e]));
        }
    }
}

__global__ __launch_bounds__(512) void k_gemm(
        const bf16x8* __restrict__ hb8, const bf16x8* __restrict__ wf8,
        const int* __restrict__ g_base, const int* __restrict__ g_count,
        const int2* __restrict__ bpack, float* __restrict__ out) {
    __shared__ float accs[64 * LDS_STRIDE];

    for (int i = threadIdx.x; i < 64 * LDS_STRIDE; i += 512) accs[i] = 0.f;
    __syncthreads();

    const int wv = threadIdx.x >> 6;      // 0..7
    const int lane = threadIdx.x & 63;
    const int m = lane & 15;
    const int q = lane >> 4;
    const f32x4 vzero = {0.f, 0.f, 0.f, 0.f};

    #pragma unroll
    for (int jr = 0; jr < 4; ++jr) {
        const int r = wv * 4 + jr;
        const int b = blockIdx.x * N_REL + r;
        const int cnt = g_count[b];
        if (cnt == 0) continue;
        const int base = g_base[b];

        bf16x8 Bf[2][4];
        #pragma unroll
        for (int kt = 0; kt < 2; ++kt)
            #pragma unroll
            for (int nt = 0; nt < 4; ++nt)
                Bf[kt][nt] = wf8[(size_t)((r * 2 + kt) * 4 + nt) * 64 + lane];

        for (int e0 = 0; e0 < cnt; e0 += 16) {
            int er = min(e0 + m, cnt - 1);
            int2 pk = bpack[base + er];
            int s = pk.x & 0xFFFF;

            bf16x8 a0 = hb8[(size_t)s * 8 + q];        // kt=0: k = q*8..q*8+7
            bf16x8 a1 = hb8[(size_t)s * 8 + 4 + q];    // kt=1: k = 32 + q*8..

            f32x4 acc[4];
            #pragma unroll
            for (int nt = 0; nt < 4; ++nt) acc[nt] = vzero;
            #pragma unroll
            for (int nt = 0; nt < 4; ++nt)
                acc[nt] = __builtin_amdgcn_mfma_f32_16x16x32_bf16(a0, Bf[0][nt], acc[nt], 0, 0, 0);
            #pragma unroll
            for (int nt = 0; nt < 4; ++nt)
                acc[nt] = __builtin_amdgcn_mfma_f32_16x16x32_bf16(a1, Bf[1][nt], acc[nt], 0, 0, 0);

            // C row = q*4+reg (edge in tile), col = nt*16+m
            #pragma unroll
            for (int reg = 0; reg < 4; ++reg) {
                int erc = e0 + q * 4 + reg;
                if (erc < cnt) {
                    int2 p2 = bpack[base + erc];
                    float nv = __int_as_float(p2.y);
                    int row = (p2.x >> 16) & 63;
                    #pragma unroll
                    for (int nt = 0; nt < 4; ++nt)
                        atomicAdd(&accs[row * LDS_STRIDE + nt * 16 + m], acc[nt][reg] * nv);
                }
            }
        }
    }

    __syncthreads();

    const int node0 = blockIdx.x * 64;
    for (int i = threadIdx.x; i < 64 * 64; i += 512) {
        int row = i >> 6;
        int col = i & 63;
        int node = node0 + row;
        if (node < N_NODES) out[(size_t)node * D + col] = accs[row * LDS_STRIDE + col];
    }
}

extern "C" void kernel_launch(void* const* d_in, const int* in_sizes, int n_in,
                              void* d_out, int out_size, void* d_ws, size_t ws_size,
                              hipStream_t stream) {
    const float* h    = (const float*)d_in[0];
    const float* W    = (const float*)d_in[1];
    const int*   src  = (const int*)d_in[2];
    const int*   dst  = (const int*)d_in[3];
    const int*   rel  = (const int*)d_in[4];
    const float* norm = (const float*)d_in[5];
    float* out = (float*)d_out;

    char* ws = (char*)d_ws;
    int* g_count  = (int*)(ws);
    int* g_base   = (int*)(ws + (size_t)NB * 4);
    int* g_cursor = (int*)(ws + (size_t)NB * 8);
    int2* bpack   = (int2*)(ws + OFF_BPACK);
    bf16x8* hb8   = (bf16x8*)(ws + OFF_HB);
    bf16x8* wf8   = (bf16x8*)(ws + OFF_WF);

    k_prep<<<PREP_BLOCKS, 256, 0, stream>>>(h, W, g_count, hb8, wf8);
    k_hist<<<HIST_BLOCKS, 256, 0, stream>>>(dst, rel, g_count);
    k_scan<<<1, 256, 0, stream>>>(g_count, g_base, g_cursor);
    k_scatter<<<HIST_BLOCKS, 256, 0, stream>>>(src, dst, rel, norm, g_cursor, bpack);
    k_gemm<<<NBLK, 512, 0, stream>>>(hb8, wf8, g_base, g_count, bpack, out);
}